// Round 6
// baseline (112.992 us; speedup 1.0000x reference)
//
#include <hip/hip_runtime.h>
#include <math.h>

#define BS 32
#define NT 50
#define NC 80
#define H 76
#define W 76
#define HW (H*W)        // 5776
#define NA (5+NC)
#define SIGMA 8.0f
#define NYB 8           // y-blocks per batch
#define CPB (HW/NYB)    // 722 cells per block, 3 chunks (256,256,210)
#define NBLK (BS*NYB)   // 256 blocks

// fast _clog: clip(log(clip(p,1e-12,1)), -100, 0) via v_log_f32
__device__ __forceinline__ float clog_(float p){
    p = fminf(fmaxf(p, 1e-12f), 1.0f);
    float l = __logf(p);
    return fminf(fmaxf(l, -100.0f), 0.0f);
}

// fast sigmoid: v_exp + v_rcp
__device__ __forceinline__ float sigmoid_(float v){
    return __builtin_amdgcn_rcpf(1.0f + __expf(-v));
}

// ---------------- Kernel 0: one-shot target prep ----------------
// tdata per target: float4[0]=box(gx1,gy1,gx2,gy2)
//                   float4[1]=rest(tx,ty,tw,th)
//                   float4[2]=meta(scale, cls, cell, area)
__global__ __launch_bounds__(64) void prep_k(
    const float* __restrict__ targets,
    float4*      __restrict__ tdata,
    int*         __restrict__ counts)
{
    const int b = blockIdx.x;
    const int t = threadIdx.x;
    __shared__ int s_cell[NT];
    __shared__ unsigned char s_valid[NT];
    __shared__ int s_count;
    if (t == 0) s_count = 0;

    float cls=0.f, xx=0.f, yy=0.f, ww=0.f, hh=0.f;
    bool valid = false;
    int cell0 = 0;
    if (t < NT){
        const float* p = targets + ((size_t)b*NT + t)*5;
        cls = p[0]; xx = p[1]; yy = p[2]; ww = p[3]; hh = p[4];
        valid = ((cls + xx + yy + ww + hh) != 0.0f);
        float gx = xx * (float)W, gy = yy * (float)H;
        int gi = min(max((int)gx, 0), W-1);
        int gj = min(max((int)gy, 0), H-1);
        cell0 = gj*W + gi;
        s_cell[t]  = cell0;
        s_valid[t] = valid ? 1 : 0;
    }
    __syncthreads();
    if (t < NT && valid){
        bool dup = false;
        for (int u = 0; u < t; ++u)
            if (s_valid[u] && s_cell[u] == cell0) dup = true;
        if (!dup){
            int idx = atomicAdd(&s_count, 1);   // LDS atomic
            float gx = xx*(float)W, gy = yy*(float)H;
            float gw = ww*(float)W, gh = hh*(float)H;
            int gi = min(max((int)gx, 0), W-1);
            int gj = min(max((int)gy, 0), H-1);
            float4* d = tdata + ((size_t)b*NT + idx)*3;
            d[0] = make_float4(gx - gw*0.5f, gy - gh*0.5f,
                               gx + gw*0.5f, gy + gh*0.5f);
            d[1] = make_float4(gx - (float)gi, gy - (float)gj,
                               logf(gw/SIGMA + 1e-16f),
                               logf(gh/SIGMA + 1e-16f));
            d[2] = make_float4(2.0f - ww*hh,
                               (float)min(max((int)cls, 0), NC-1),
                               (float)cell0,
                               gw * gh);
        }
    }
    __syncthreads();
    if (t == 0) counts[b] = s_count;
}

// per-cell epilogue helper
struct Acc { float lx, ly, lw, lh, lc; };
__device__ __forceinline__ void cell_loss(
    Acc& a, const float4* s_t4, int myt, bool ignore,
    float x, float y, float vw, float vh, float conf)
{
    if (myt >= 0){
        float4 r    = s_t4[3*myt+1];
        float scale = s_t4[3*myt+2].x;
        a.lx += scale * (-(r.x*clog_(x) + (1.f-r.x)*clog_(1.f-x)));
        a.ly += scale * (-(r.y*clog_(y) + (1.f-r.y)*clog_(1.f-y)));
        float dw = fabsf(vw - r.z);
        a.lw += scale * (dw < 1.f ? 0.5f*dw*dw : dw - 0.5f);
        float dh = fabsf(vh - r.w);
        a.lh += scale * (dh < 1.f ? 0.5f*dh*dh : dh - 0.5f);
        a.lc += -clog_(conf);
    } else if (!ignore){
        a.lc += 0.5f * (-clog_(1.0f - conf));
    }
}

// ---------------- Kernel 1: 3 cells/thread, ILP-restructured ----------------
// partials layout: partials[j*NBLK + bid], j in 0..5 = {x,y,w,h,conf,tcls}
__global__ __launch_bounds__(256) void yolo_main(
    const float*  __restrict__ input,
    const float4* __restrict__ tdata,
    const int*    __restrict__ counts,
    float*        __restrict__ partials)
{
    const int b   = blockIdx.x;
    const int yb  = blockIdx.y;
    const int tid = threadIdx.x;
    const int bid = b * NYB + yb;

    __shared__ float4 s_t4[NT*3];
    __shared__ int s_nb;
    if (tid < NT*3) s_t4[tid] = tdata[(size_t)b*NT*3 + tid];
    if (tid == 0)   s_nb = counts[b];

    const int blockLo = yb * CPB;
    const int blockHi = blockLo + CPB;
    const float* binp = input + (size_t)b*NA*HW;

    const int  cell0 = blockLo + tid;
    const int  cell1 = cell0 + 256;
    const bool in2   = (tid < CPB - 512);          // 210 lanes
    const int  cell2 = in2 ? (cell0 + 512) : cell0; // safe dup addr; guarded

    // early channel loads — 15 independent loads in flight across the barrier
    float vx0=binp[cell0], vy0=binp[HW+cell0], vw0=binp[2*HW+cell0],
          vh0=binp[3*HW+cell0], vc0=binp[4*HW+cell0];
    float vx1=binp[cell1], vy1=binp[HW+cell1], vw1=binp[2*HW+cell1],
          vh1=binp[3*HW+cell1], vc1=binp[4*HW+cell1];
    float vx2=binp[cell2], vy2=binp[HW+cell2], vw2=binp[2*HW+cell2],
          vh2=binp[3*HW+cell2], vc2=binp[4*HW+cell2];

    __syncthreads();
    const int nb = s_nb;

    // ---- cooperative tcls: only waves 0-1 (tid<80); waves 2-3 proceed to IoU ----
    float lt = 0.f;
    if (tid < NC){
        for (int t = 0; t < nb; ++t){
            float4 meta = s_t4[3*t+2];          // broadcast LDS read
            int q = (int)meta.z;
            if (q >= blockLo && q < blockHi){
                float pc  = sigmoid_(binp[(size_t)(5+tid)*HW + q]);
                float arg = (tid == (int)meta.y) ? pc : 1.f - pc;
                lt += -clog_(arg);
            }
        }
    }

    // ---- per-chunk box params ----
    float x0 = sigmoid_(vx0), y0 = sigmoid_(vy0), cf0 = sigmoid_(vc0);
    float x1 = sigmoid_(vx1), y1 = sigmoid_(vy1), cf1 = sigmoid_(vc1);
    float x2 = sigmoid_(vx2), y2 = sigmoid_(vy2), cf2 = sigmoid_(vc2);
    float pw0 = __expf(vw0)*SIGMA, ph0 = __expf(vh0)*SIGMA;
    float pw1 = __expf(vw1)*SIGMA, ph1 = __expf(vh1)*SIGMA;
    float pw2 = __expf(vw2)*SIGMA, ph2 = __expf(vh2)*SIGMA;

    int i0 = cell0 / W, j0 = cell0 - i0*W;
    int i1 = cell1 / W, j1 = cell1 - i1*W;
    int i2 = cell2 / W, j2 = cell2 - i2*W;

    float px10 = x0 + j0 - pw0*0.5f, px20 = x0 + j0 + pw0*0.5f;
    float py10 = y0 + i0 - ph0*0.5f, py20 = y0 + i0 + ph0*0.5f;
    float pa0  = pw0 * ph0;
    float px11 = x1 + j1 - pw1*0.5f, px21 = x1 + j1 + pw1*0.5f;
    float py11 = y1 + i1 - ph1*0.5f, py21 = y1 + i1 + ph1*0.5f;
    float pa1  = pw1 * ph1;
    float px12 = x2 + j2 - pw2*0.5f, px22 = x2 + j2 + pw2*0.5f;
    float py12 = y2 + i2 - ph2*0.5f, py22 = y2 + i2 + ph2*0.5f;
    float pa2  = pw2 * ph2;

    // ---- IoU scan: one LDS round per target feeds 3 independent chains ----
    bool ig0=false, ig1=false, ig2=false;
    int  myt0=-1,  myt1=-1,  myt2=-1;
    for (int t = 0; t < nb; ++t){
        float4 bx   = s_t4[3*t];                // ds_read_b128, broadcast
        float4 meta = s_t4[3*t+2];
        int qc = (int)meta.z;
        {
            float iw = fminf(bx.z, px20) - fmaxf(bx.x, px10);
            float ih = fminf(bx.w, py20) - fmaxf(bx.y, py10);
            float inter = fmaxf(iw,0.f)*fmaxf(ih,0.f);
            ig0 = ig0 || (inter >= 0.5f*(meta.w + pa0 - inter + 1e-16f));
            if (qc == cell0) myt0 = t;
        }
        {
            float iw = fminf(bx.z, px21) - fmaxf(bx.x, px11);
            float ih = fminf(bx.w, py21) - fmaxf(bx.y, py11);
            float inter = fmaxf(iw,0.f)*fmaxf(ih,0.f);
            ig1 = ig1 || (inter >= 0.5f*(meta.w + pa1 - inter + 1e-16f));
            if (qc == cell1) myt1 = t;
        }
        {
            float iw = fminf(bx.z, px22) - fmaxf(bx.x, px12);
            float ih = fminf(bx.w, py22) - fmaxf(bx.y, py12);
            float inter = fmaxf(iw,0.f)*fmaxf(ih,0.f);
            ig2 = ig2 || (inter >= 0.5f*(meta.w + pa2 - inter + 1e-16f));
            if (in2 && qc == cell2) myt2 = t;
        }
    }

    // ---- epilogues ----
    Acc a = {0.f,0.f,0.f,0.f,0.f};
    cell_loss(a, s_t4, myt0, ig0, x0, y0, vw0, vh0, cf0);
    cell_loss(a, s_t4, myt1, ig1, x1, y1, vw1, vh1, cf1);
    if (in2) cell_loss(a, s_t4, myt2, ig2, x2, y2, vw2, vh2, cf2);

    // ---- block reduction: wave shuffle, then cross-wave via LDS ----
    float lx=a.lx, ly=a.ly, lw=a.lw, lh=a.lh, lc=a.lc;
    #pragma unroll
    for (int off = 32; off > 0; off >>= 1){
        lx += __shfl_down(lx, off);
        ly += __shfl_down(ly, off);
        lw += __shfl_down(lw, off);
        lh += __shfl_down(lh, off);
        lc += __shfl_down(lc, off);
        lt += __shfl_down(lt, off);
    }
    __shared__ float s_red[4*6];
    if ((tid & 63) == 0){
        int wv = tid >> 6;
        s_red[wv*6+0] = lx; s_red[wv*6+1] = ly; s_red[wv*6+2] = lw;
        s_red[wv*6+3] = lh; s_red[wv*6+4] = lc; s_red[wv*6+5] = lt;
    }
    __syncthreads();
    if (tid < 6){
        float v = s_red[tid] + s_red[6+tid] + s_red[12+tid] + s_red[18+tid];
        partials[tid*NBLK + bid] = v;          // block-unique slot, no atomics
    }
}

// ---------------- Kernel 2: final reduce over 256 blocks + n_obj + output ----------------
__global__ __launch_bounds__(256) void finalize_k(
    const float* __restrict__ partials,
    const int*   __restrict__ counts,
    float*       __restrict__ out)
{
    int tid = threadIdx.x;
    float loc[6];
    #pragma unroll
    for (int j = 0; j < 6; ++j) loc[j] = partials[j*NBLK + tid];
    float nloc = (tid < BS) ? (float)counts[tid] : 0.f;

    #pragma unroll
    for (int off = 32; off > 0; off >>= 1){
        #pragma unroll
        for (int j = 0; j < 6; ++j) loc[j] += __shfl_down(loc[j], off);
        nloc += __shfl_down(nloc, off);
    }
    __shared__ float s_red[4*7];
    if ((tid & 63) == 0){
        int wv = tid >> 6;
        #pragma unroll
        for (int j = 0; j < 6; ++j) s_red[wv*7+j] = loc[j];
        s_red[wv*7+6] = nloc;
    }
    __syncthreads();
    if (tid == 0){
        float s[7];
        #pragma unroll
        for (int j = 0; j < 7; ++j)
            s[j] = s_red[j] + s_red[7+j] + s_red[14+j] + s_red[21+j];
        float n = s[6];
        float inv = (n > 0.f) ? (1.0f / n) : 0.0f;
        float lx = s[0]*inv, ly = s[1]*inv, lw = s[2]*inv, lh = s[3]*inv;
        float lconf = s[4]*inv;
        float ltcls = (n > 0.f) ? s[5]*inv : 0.0f;
        out[0] = lx + ly + lw + lh + lconf + ltcls;
        out[1] = lx;
        out[2] = ly;
        out[3] = lw;
        out[4] = lh;
        out[5] = lconf;
        out[6] = ltcls;
    }
}

extern "C" void kernel_launch(void* const* d_in, const int* in_sizes, int n_in,
                              void* d_out, int out_size, void* d_ws, size_t ws_size,
                              hipStream_t stream) {
    const float* input   = (const float*)d_in[0];
    const float* targets = (const float*)d_in[1];
    float* out = (float*)d_out;

    // ws layout:
    // [0 .. 76800)              tdata: 32*50*3 float4
    // [76800 .. 76800+6144)     partials: 6*NBLK floats
    // [82944 .. 83072)          counts[32]
    float4* tdata    = (float4*)d_ws;
    float*  partials = (float*)((char*)d_ws + 76800);
    int*    counts   = (int*)((char*)d_ws + 76800 + 6*NBLK*sizeof(float));

    prep_k<<<dim3(BS), dim3(64), 0, stream>>>(targets, tdata, counts);

    dim3 grid(BS, NYB);
    yolo_main<<<grid, dim3(256), 0, stream>>>(input, tdata, counts, partials);

    finalize_k<<<1, dim3(256), 0, stream>>>(partials, counts, out);
}

// Round 7
// 109.723 us; speedup vs baseline: 1.0298x; 1.0298x over previous
//
#include <hip/hip_runtime.h>
#include <math.h>

#define BS 32
#define NT 50
#define NC 80
#define H 76
#define W 76
#define HW (H*W)
#define NA (5+NC)
#define SIGMA 8.0f
#define YBLK 23          // ceil(HW/256)
#define NBLK (BS*YBLK)   // 736

// fast _clog: clip(log(clip(p,1e-12,1)), -100, 0) via v_log_f32
__device__ __forceinline__ float clog_(float p){
    p = fminf(fmaxf(p, 1e-12f), 1.0f);
    float l = __logf(p);
    return fminf(fmaxf(l, -100.0f), 0.0f);
}

// fast sigmoid: v_exp_f32 + v_rcp_f32
__device__ __forceinline__ float sigmoid_(float v){
    return __builtin_amdgcn_rcpf(1.0f + __expf(-v));
}

// ---------------- Kernel 0: one-shot target prep (libm — off hot path) ----------------
// tdata per target: float4[0]=box(gx1,gy1,gx2,gy2)
//                   float4[1]=rest(tx,ty,tw,th)
//                   float4[2]=meta(scale, cls, cell, area)
__global__ __launch_bounds__(64) void prep_k(
    const float* __restrict__ targets,
    float4*      __restrict__ tdata,
    int*         __restrict__ counts)
{
    const int b = blockIdx.x;
    const int t = threadIdx.x;
    __shared__ int s_cell[NT];
    __shared__ unsigned char s_valid[NT];
    __shared__ int s_count;
    if (t == 0) s_count = 0;

    float cls=0.f, xx=0.f, yy=0.f, ww=0.f, hh=0.f;
    bool valid = false;
    int cell0 = 0;
    if (t < NT){
        const float* p = targets + ((size_t)b*NT + t)*5;
        cls = p[0]; xx = p[1]; yy = p[2]; ww = p[3]; hh = p[4];
        valid = ((cls + xx + yy + ww + hh) != 0.0f);
        float gx = xx * (float)W, gy = yy * (float)H;
        int gi = min(max((int)gx, 0), W-1);
        int gj = min(max((int)gy, 0), H-1);
        cell0 = gj*W + gi;
        s_cell[t]  = cell0;
        s_valid[t] = valid ? 1 : 0;
    }
    __syncthreads();
    if (t < NT && valid){
        bool dup = false;
        for (int u = 0; u < t; ++u)
            if (s_valid[u] && s_cell[u] == cell0) dup = true;
        if (!dup){
            int idx = atomicAdd(&s_count, 1);   // LDS atomic
            float gx = xx*(float)W, gy = yy*(float)H;
            float gw = ww*(float)W, gh = hh*(float)H;
            int gi = min(max((int)gx, 0), W-1);
            int gj = min(max((int)gy, 0), H-1);
            float4* d = tdata + ((size_t)b*NT + idx)*3;
            d[0] = make_float4(gx - gw*0.5f, gy - gh*0.5f,
                               gx + gw*0.5f, gy + gh*0.5f);
            d[1] = make_float4(gx - (float)gi, gy - (float)gj,
                               logf(gw/SIGMA + 1e-16f),
                               logf(gh/SIGMA + 1e-16f));
            d[2] = make_float4(2.0f - ww*hh,
                               (float)min(max((int)cls, 0), NC-1),
                               (float)cell0,
                               gw * gh);
        }
    }
    __syncthreads();
    if (t == 0) counts[b] = s_count;
}

// ---------------- Kernel 1: per-cell loss + cooperative tcls ----------------
// partials layout: partials[j*NBLK + bid], j in 0..5 = {x,y,w,h,conf,tcls}
__global__ __launch_bounds__(256) void yolo_main(
    const float*  __restrict__ input,
    const float4* __restrict__ tdata,
    const int*    __restrict__ counts,
    float*        __restrict__ partials)
{
    const int b   = blockIdx.x;
    const int yb  = blockIdx.y;
    const int tid = threadIdx.x;
    const int bid = b * YBLK + yb;

    __shared__ float4 s_t4[NT*3];
    __shared__ int s_nb;

    // stage target records (coalesced, one round) + count
    if (tid < NT*3) s_t4[tid] = tdata[(size_t)b*NT*3 + tid];
    if (tid == 0)   s_nb = counts[b];

    // issue per-cell channel loads early: latency overlaps staging+barrier
    const int cellLo = yb * 256;
    const int cell   = cellLo + tid;
    const float* binp = input + (size_t)b*NA*HW;
    float vx=0.f, vy=0.f, vw=0.f, vh=0.f, vc=0.f;
    const bool incell = (cell < HW);
    if (incell){
        const float* base = binp + cell;
        vx = base[0];
        vy = base[HW];
        vw = base[2*HW];
        vh = base[3*HW];
        vc = base[4*HW];
    }
    __syncthreads();
    const int nb = s_nb;

    float lx=0.f, ly=0.f, lw=0.f, lh=0.f, lc=0.f, lt=0.f;

    // ---- cooperative tcls: lane c (<80) loads class channel c for each
    // object in this block's cell range -> 80 loads in flight at once.
    const int cellHi = (cellLo + 256 < HW) ? cellLo + 256 : HW;
    for (int t = 0; t < nb; ++t){
        float4 meta = s_t4[3*t+2];              // broadcast LDS read
        int q = (int)meta.z;
        if (q >= cellLo && q < cellHi && tid < NC){
            float pc = sigmoid_(binp[(size_t)(5+tid)*HW + q]);
            int cidx = (int)meta.y;
            lt += (tid == cidx) ? -clog_(pc) : -clog_(1.f - pc);
        }
    }

    // ---- per-cell loss ----
    if (incell){
        float x    = sigmoid_(vx);
        float y    = sigmoid_(vy);
        float conf = sigmoid_(vc);
        int i = cell / W, j = cell - i*W;
        float pw = __expf(vw) * SIGMA;
        float ph = __expf(vh) * SIGMA;
        float px = x + (float)j;
        float py = y + (float)i;
        float px1 = px - pw*0.5f, px2 = px + pw*0.5f;
        float py1 = py - ph*0.5f, py2 = py + ph*0.5f;
        float parea = pw * ph;

        bool ignore = false;
        int myt = -1;
        for (int t = 0; t < nb; ++t){
            float4 bx   = s_t4[3*t];            // broadcast ds_read_b128
            float4 meta = s_t4[3*t+2];
            float iw = fminf(bx.z, px2) - fmaxf(bx.x, px1);
            float ih = fminf(bx.w, py2) - fmaxf(bx.y, py1);
            iw = fmaxf(iw, 0.f); ih = fmaxf(ih, 0.f);
            float inter = iw * ih;
            // iou >= 0.5  <=>  inter >= 0.5*(area + parea - inter + eps)
            ignore = ignore || (inter >= 0.5f*(meta.w + parea - inter + 1e-16f));
            if ((int)meta.z == cell) myt = t;
        }

        if (myt >= 0){
            float4 r    = s_t4[3*myt+1];
            float scale = s_t4[3*myt+2].x;
            lx = scale * (-(r.x*clog_(x) + (1.f-r.x)*clog_(1.f-x)));
            ly = scale * (-(r.y*clog_(y) + (1.f-r.y)*clog_(1.f-y)));
            float dw = fabsf(vw - r.z);
            lw = scale * (dw < 1.f ? 0.5f*dw*dw : dw - 0.5f);
            float dh = fabsf(vh - r.w);
            lh = scale * (dh < 1.f ? 0.5f*dh*dh : dh - 0.5f);
            lc = -clog_(conf);
        } else if (!ignore){
            lc = 0.5f * (-clog_(1.0f - conf));
        }
    }

    // ---- block reduction: wave shuffle, then cross-wave via LDS ----
    #pragma unroll
    for (int off = 32; off > 0; off >>= 1){
        lx += __shfl_down(lx, off);
        ly += __shfl_down(ly, off);
        lw += __shfl_down(lw, off);
        lh += __shfl_down(lh, off);
        lc += __shfl_down(lc, off);
        lt += __shfl_down(lt, off);
    }
    __shared__ float s_red[4*6];
    if ((tid & 63) == 0){
        int wv = tid >> 6;
        s_red[wv*6+0] = lx; s_red[wv*6+1] = ly; s_red[wv*6+2] = lw;
        s_red[wv*6+3] = lh; s_red[wv*6+4] = lc; s_red[wv*6+5] = lt;
    }
    __syncthreads();
    if (tid < 6){
        float v = s_red[tid] + s_red[6+tid] + s_red[12+tid] + s_red[18+tid];
        partials[tid*NBLK + bid] = v;          // block-unique slot, no atomics
    }
}

// ---------------- Kernel 2: final reduce over 736 blocks + n_obj + output ----------------
__global__ __launch_bounds__(256) void finalize_k(
    const float* __restrict__ partials,
    const int*   __restrict__ counts,
    float*       __restrict__ out)
{
    int tid = threadIdx.x;
    float loc[6] = {0,0,0,0,0,0};
    for (int k = tid; k < NBLK; k += 256){
        #pragma unroll
        for (int j = 0; j < 6; ++j) loc[j] += partials[j*NBLK + k];
    }
    float nloc = (tid < BS) ? (float)counts[tid] : 0.f;

    #pragma unroll
    for (int off = 32; off > 0; off >>= 1){
        #pragma unroll
        for (int j = 0; j < 6; ++j) loc[j] += __shfl_down(loc[j], off);
        nloc += __shfl_down(nloc, off);
    }
    __shared__ float s_red[4*7];
    if ((tid & 63) == 0){
        int wv = tid >> 6;
        #pragma unroll
        for (int j = 0; j < 6; ++j) s_red[wv*7+j] = loc[j];
        s_red[wv*7+6] = nloc;
    }
    __syncthreads();
    if (tid == 0){
        float s[7];
        #pragma unroll
        for (int j = 0; j < 7; ++j)
            s[j] = s_red[j] + s_red[7+j] + s_red[14+j] + s_red[21+j];
        float n = s[6];
        float inv = (n > 0.f) ? (1.0f / n) : 0.0f;
        float lx = s[0]*inv, ly = s[1]*inv, lw = s[2]*inv, lh = s[3]*inv;
        float lconf = s[4]*inv;
        float ltcls = (n > 0.f) ? s[5]*inv : 0.0f;
        out[0] = lx + ly + lw + lh + lconf + ltcls;
        out[1] = lx;
        out[2] = ly;
        out[3] = lw;
        out[4] = lh;
        out[5] = lconf;
        out[6] = ltcls;
    }
}

extern "C" void kernel_launch(void* const* d_in, const int* in_sizes, int n_in,
                              void* d_out, int out_size, void* d_ws, size_t ws_size,
                              hipStream_t stream) {
    const float* input   = (const float*)d_in[0];
    const float* targets = (const float*)d_in[1];
    float* out = (float*)d_out;

    // ws layout:
    // [0 .. 76800)            tdata: 32*50*3 float4
    // [76800 .. 76800+17664)  partials: 6*NBLK floats
    // [94464 .. 94592)        counts[32]
    float4* tdata    = (float4*)d_ws;
    float*  partials = (float*)((char*)d_ws + 76800);
    int*    counts   = (int*)((char*)d_ws + 76800 + 6*NBLK*sizeof(float));

    prep_k<<<dim3(BS), dim3(64), 0, stream>>>(targets, tdata, counts);

    dim3 grid(BS, YBLK);
    yolo_main<<<grid, dim3(256), 0, stream>>>(input, tdata, counts, partials);

    finalize_k<<<1, dim3(256), 0, stream>>>(partials, counts, out);
}

// Round 8
// 108.070 us; speedup vs baseline: 1.0455x; 1.0153x over previous
//
#include <hip/hip_runtime.h>
#include <math.h>

#define BS 32
#define NT 50
#define NC 80
#define H 76
#define W 76
#define HW (H*W)
#define NA (5+NC)
#define SIGMA 8.0f
#define YBLK 23          // ceil(HW/256)
#define NBLK (BS*YBLK)   // 736

// _clog: clip(log(clip(p,1e-12,1)), -100, 0)
__device__ __forceinline__ float clog_(float p){
    p = fminf(fmaxf(p, 1e-12f), 1.0f);
    float l = logf(p);
    return fminf(fmaxf(l, -100.0f), 0.0f);
}

__device__ __forceinline__ float sigmoid_(float v){
    return 1.0f / (1.0f + expf(-v));
}

// ---------------- Kernel 1: prep + per-cell loss + cooperative tcls ----------------
// partials layout: partials[j*NBLK + bid], j in 0..5 = {x,y,w,h,conf,tcls}
__global__ __launch_bounds__(256) void yolo_main(
    const float* __restrict__ input,
    const float* __restrict__ targets,
    float*       __restrict__ partials,
    int*         __restrict__ counts)
{
    const int b   = blockIdx.x;
    const int yb  = blockIdx.y;
    const int tid = threadIdx.x;
    const int bid = b * YBLK + yb;

    // ---- in-block target prep (redundant per block; tiny) ----
    __shared__ float4 s_box[NT];         // gx1,gy1,gx2,gy2 (compacted)
    __shared__ int    s_cellc[NT];       // cell id (compacted)
    __shared__ float4 s_rest[NT];        // tx,ty,tw,th
    __shared__ float2 s_sc[NT];          // scale, cls
    __shared__ int    s_cell[NT];
    __shared__ unsigned char s_valid[NT];
    __shared__ int    s_count;

    if (tid == 0) s_count = 0;

    float cls=0.f, xx=0.f, yy=0.f, ww=0.f, hh=0.f;
    bool valid = false;
    int cell0 = 0;
    if (tid < NT){
        const float* p = targets + ((size_t)b*NT + tid)*5;
        cls = p[0]; xx = p[1]; yy = p[2]; ww = p[3]; hh = p[4];
        valid = ((cls + xx + yy + ww + hh) != 0.0f);
        float gx = xx * (float)W, gy = yy * (float)H;
        int gi = min(max((int)gx, 0), W-1);
        int gj = min(max((int)gy, 0), H-1);
        cell0 = gj*W + gi;
        s_cell[tid]  = cell0;
        s_valid[tid] = valid ? 1 : 0;
    }
    __syncthreads();
    if (tid < NT && valid){
        bool dup = false;
        for (int u = 0; u < tid; ++u)
            if (s_valid[u] && s_cell[u] == cell0) dup = true;
        if (!dup){
            int idx = atomicAdd(&s_count, 1);   // LDS atomic — cheap
            float gx = xx*(float)W, gy = yy*(float)H;
            float gw = ww*(float)W, gh = hh*(float)H;
            int gi = min(max((int)gx, 0), W-1);
            int gj = min(max((int)gy, 0), H-1);
            s_box[idx]  = make_float4(gx - gw*0.5f, gy - gh*0.5f,
                                      gx + gw*0.5f, gy + gh*0.5f);
            s_cellc[idx]= cell0;
            s_rest[idx] = make_float4(gx - (float)gi, gy - (float)gj,
                                      logf(gw/SIGMA + 1e-16f),
                                      logf(gh/SIGMA + 1e-16f));
            s_sc[idx]   = make_float2(2.0f - ww*hh,
                                      (float)min(max((int)cls, 0), NC-1));
        }
    }
    __syncthreads();
    const int nb = s_count;

    float lx=0.f, ly=0.f, lw=0.f, lh=0.f, lc=0.f, lt=0.f;

    const int cellLo = yb * 256;
    const int cellHi = (cellLo + 256 < HW) ? cellLo + 256 : HW;
    const float* binp = input + (size_t)b*NA*HW;

    // ---- cooperative tcls: for each object in this block's cell range,
    // lane c (<80) loads class channel c -> 80 strided loads in flight at once.
    for (int t = 0; t < nb; ++t){
        int q = s_cellc[t];
        if (q >= cellLo && q < cellHi && tid < NC){      // wave-uniform except lane split
            float pc = sigmoid_(binp[(size_t)(5+tid)*HW + q]);
            int cidx = (int)s_sc[t].y;                   // broadcast LDS read
            lt += (tid == cidx) ? -clog_(pc) : -clog_(1.f - pc);
        }
    }

    // ---- per-cell loss (no class loop here) ----
    const int cell = cellLo + tid;
    if (cell < HW){
        const float* base = binp + cell;
        float vx = base[0];
        float vy = base[HW];
        float vw = base[2*HW];
        float vh = base[3*HW];
        float vc = base[4*HW];
        float x    = sigmoid_(vx);
        float y    = sigmoid_(vy);
        float conf = sigmoid_(vc);
        int i = cell / W, j = cell - i*W;
        float pw = expf(vw) * SIGMA;
        float ph = expf(vh) * SIGMA;
        float px = x + (float)j;
        float py = y + (float)i;
        float px1 = px - pw*0.5f, px2 = px + pw*0.5f;
        float py1 = py - ph*0.5f, py2 = py + ph*0.5f;
        float parea = pw * ph;

        bool ignore = false;
        int myt = -1;
        for (int t = 0; t < nb; ++t){
            float4 bx = s_box[t];               // broadcast ds_read_b128
            float garea = (bx.z - bx.x) * (bx.w - bx.y);
            float iw = fminf(bx.z, px2) - fmaxf(bx.x, px1);
            float ih = fminf(bx.w, py2) - fmaxf(bx.y, py1);
            iw = fmaxf(iw, 0.f); ih = fmaxf(ih, 0.f);
            float inter = iw * ih;
            // iou >= 0.5  <=>  inter >= 0.5*(garea + parea - inter + eps)
            ignore = ignore || (inter >= 0.5f*(garea + parea - inter + 1e-16f));
            if (s_cellc[t] == cell) myt = t;
        }

        if (myt >= 0){
            float4 r = s_rest[myt];
            float scale = s_sc[myt].x;
            lx = scale * (-(r.x*clog_(x) + (1.f-r.x)*clog_(1.f-x)));
            ly = scale * (-(r.y*clog_(y) + (1.f-r.y)*clog_(1.f-y)));
            float dw = fabsf(vw - r.z);
            lw = scale * (dw < 1.f ? 0.5f*dw*dw : dw - 0.5f);
            float dh = fabsf(vh - r.w);
            lh = scale * (dh < 1.f ? 0.5f*dh*dh : dh - 0.5f);
            lc = -clog_(conf);
        } else if (!ignore){
            lc = 0.5f * (-clog_(1.0f - conf));
        }
    }

    // ---- block reduction: wave shuffle, then cross-wave via LDS, plain stores ----
    #pragma unroll
    for (int off = 32; off > 0; off >>= 1){
        lx += __shfl_down(lx, off);
        ly += __shfl_down(ly, off);
        lw += __shfl_down(lw, off);
        lh += __shfl_down(lh, off);
        lc += __shfl_down(lc, off);
        lt += __shfl_down(lt, off);
    }
    __shared__ float s_red[4*6];
    if ((tid & 63) == 0){
        int wv = tid >> 6;
        s_red[wv*6+0] = lx; s_red[wv*6+1] = ly; s_red[wv*6+2] = lw;
        s_red[wv*6+3] = lh; s_red[wv*6+4] = lc; s_red[wv*6+5] = lt;
    }
    __syncthreads();
    if (tid < 6){
        float v = s_red[tid] + s_red[6+tid] + s_red[12+tid] + s_red[18+tid];
        partials[tid*NBLK + bid] = v;          // block-unique slot, no atomics
    }
    if (yb == 0 && tid == 0) counts[b] = nb;
}

// ---------------- Kernel 2: final reduce over 736 blocks + n_obj + output ----------------
__global__ __launch_bounds__(256) void finalize_k(
    const float* __restrict__ partials,
    const int*   __restrict__ counts,
    float*       __restrict__ out)
{
    int tid = threadIdx.x;
    float loc[6] = {0,0,0,0,0,0};
    for (int k = tid; k < NBLK; k += 256){
        #pragma unroll
        for (int j = 0; j < 6; ++j) loc[j] += partials[j*NBLK + k];
    }
    float nloc = (tid < BS) ? (float)counts[tid] : 0.f;

    #pragma unroll
    for (int off = 32; off > 0; off >>= 1){
        #pragma unroll
        for (int j = 0; j < 6; ++j) loc[j] += __shfl_down(loc[j], off);
        nloc += __shfl_down(nloc, off);
    }
    __shared__ float s_red[4*7];
    if ((tid & 63) == 0){
        int wv = tid >> 6;
        #pragma unroll
        for (int j = 0; j < 6; ++j) s_red[wv*7+j] = loc[j];
        s_red[wv*7+6] = nloc;
    }
    __syncthreads();
    if (tid == 0){
        float s[7];
        #pragma unroll
        for (int j = 0; j < 7; ++j)
            s[j] = s_red[j] + s_red[7+j] + s_red[14+j] + s_red[21+j];
        float n = s[6];
        float inv = (n > 0.f) ? (1.0f / n) : 0.0f;
        float lx = s[0]*inv, ly = s[1]*inv, lw = s[2]*inv, lh = s[3]*inv;
        float lconf = s[4]*inv;
        float ltcls = (n > 0.f) ? s[5]*inv : 0.0f;
        out[0] = lx + ly + lw + lh + lconf + ltcls;
        out[1] = lx;
        out[2] = ly;
        out[3] = lw;
        out[4] = lh;
        out[5] = lconf;
        out[6] = ltcls;
    }
}

extern "C" void kernel_launch(void* const* d_in, const int* in_sizes, int n_in,
                              void* d_out, int out_size, void* d_ws, size_t ws_size,
                              hipStream_t stream) {
    const float* input   = (const float*)d_in[0];
    const float* targets = (const float*)d_in[1];
    float* out = (float*)d_out;

    // ws layout: [0 .. 6*NBLK*4) partials | then counts[32]
    float* partials = (float*)d_ws;
    int*   counts   = (int*)((char*)d_ws + 6*NBLK*sizeof(float));

    dim3 grid(BS, YBLK);
    yolo_main<<<grid, dim3(256), 0, stream>>>(input, targets, partials, counts);
    finalize_k<<<1, dim3(256), 0, stream>>>(partials, counts, out);
}